// Round 16
// baseline (76.562 us; speedup 1.0000x reference)
//
#include <hip/hip_runtime.h>
#include <hip/hip_bf16.h>
#include <math.h>

#define NB 16
#define NLC 1024
#define NLQ 128
#define ND 512
#define NEGV (-1.0e10f)

typedef __attribute__((ext_vector_type(8))) short bf16x8f;
typedef __attribute__((ext_vector_type(4))) float f32x4a;

__device__ inline unsigned short f2bf(float f) {
    unsigned u = __float_as_uint(f);
    unsigned r = (u + 0x7fffu + ((u >> 16) & 1u)) >> 16;
    return (unsigned short)r;
}

// XCD-locality swizzle (m157 bijective form, nwg % 8 == 0).
__device__ inline int xcd_swz(int bid, int nwg) {
    int chunk = nwg >> 3;
    return (bid & 7) * chunk + (bid >> 3);
}

// ---------------------------------------------------------------------------
// k_prep2 (512 thr, 64-row x 256-d tiles, 576 blocks): single pass:
//   Cb16 bf16 [b][i][d] = C ; Ct bf16 [b][d][i] = C^T ; scp = partial C@w1
//   Qw3  bf16 [b][j][d] = Q*w3 ; Qt bf16 [b][d][j] = Q^T ; sqp = partial Q@w2
__global__ __launch_bounds__(512) void k_prep2(const float* __restrict__ C,
                                               const float* __restrict__ Q,
                                               const float* __restrict__ w,
                                               unsigned short* __restrict__ Cb16,
                                               unsigned short* __restrict__ Ct,
                                               unsigned short* __restrict__ Qw3,
                                               unsigned short* __restrict__ Qt,
                                               float* __restrict__ scp,
                                               float* __restrict__ sqp) {
    __shared__ float T[64][65];
    int x = blockIdx.x, t = threadIdx.x;
    const float* src; const float* wdot; const float* wmul;
    unsigned short* rout; unsigned short* tout; float* sdst;
    int rows;
    if (x < 512) {
        int b = x >> 5, rt = (x >> 1) & 15, dh = x & 1;
        src = C + ((size_t)b * NLC + rt * 64) * ND + dh * 256;
        wdot = w + dh * 256;
        wmul = nullptr;                     // plain bf16(C)
        rout = Cb16 + ((size_t)b * NLC + rt * 64) * ND + dh * 256;
        tout = Ct + ((size_t)b * ND + dh * 256) * NLC + rt * 64;
        sdst = scp + dh * (NB * NLC) + b * NLC + rt * 64;
        rows = NLC;
    } else {
        int xq = x - 512;
        int b = xq >> 2, rt = (xq >> 1) & 1, dh = xq & 1;
        src = Q + ((size_t)b * NLQ + rt * 64) * ND + dh * 256;
        wdot = w + ND + dh * 256;
        wmul = w + 2 * ND + dh * 256;       // bf16(Q*w3)
        rout = Qw3 + ((size_t)b * NLQ + rt * 64) * ND + dh * 256;
        tout = Qt + ((size_t)b * ND + dh * 256) * NLQ + rt * 64;
        sdst = sqp + dh * (NB * NLQ) + b * NLQ + rt * 64;
        rows = NLQ;
    }
    int r = t >> 3;          // 0..63 row in tile
    int s8 = (t & 7) * 8;    // col offset within 64-d chunk
    float dacc = 0.f;
    for (int c = 0; c < 4; ++c) {   // 4 x 64-d chunks = 256 d
        int dbase = c * 64 + s8;
        float4 v0 = *(const float4*)&src[(size_t)r * ND + dbase];
        float4 v1 = *(const float4*)&src[(size_t)r * ND + dbase + 4];
        float4 wd0 = *(const float4*)&wdot[dbase];
        float4 wd1 = *(const float4*)&wdot[dbase + 4];
        dacc += v0.x * wd0.x + v0.y * wd0.y + v0.z * wd0.z + v0.w * wd0.w;
        dacc += v1.x * wd1.x + v1.y * wd1.y + v1.z * wd1.z + v1.w * wd1.w;
        float f8[8] = {v0.x, v0.y, v0.z, v0.w, v1.x, v1.y, v1.z, v1.w};
        unsigned short o[8];
        if (wmul) {
            float4 w30 = *(const float4*)&wmul[dbase];
            float4 w31 = *(const float4*)&wmul[dbase + 4];
            float m8[8] = {w30.x, w30.y, w30.z, w30.w, w31.x, w31.y, w31.z, w31.w};
#pragma unroll
            for (int e = 0; e < 8; ++e) o[e] = f2bf(f8[e] * m8[e]);
        } else {
#pragma unroll
            for (int e = 0; e < 8; ++e) o[e] = f2bf(f8[e]);
        }
        *(int4*)&rout[(size_t)r * ND + dbase] = *(int4*)o;
#pragma unroll
        for (int e = 0; e < 8; ++e) T[r][s8 + e] = f8[e];
        __syncthreads();
        {   // transposed bf16 out: d-row = c*64+dd, full 128B line per row
            int dd = t >> 3, seg = (t & 7) * 8;
            unsigned short o16[8];
#pragma unroll
            for (int e = 0; e < 8; ++e) o16[e] = f2bf(T[seg + e][dd]);
            *(int4*)&tout[(size_t)(c * 64 + dd) * rows + seg] = *(int4*)o16;
        }
        __syncthreads();
    }
    dacc += __shfl_xor(dacc, 1, 64);
    dacc += __shfl_xor(dacc, 2, 64);
    dacc += __shfl_xor(dacc, 4, 64);
    if ((t & 7) == 0) sdst[r] = dacc;
}

// ---------------------------------------------------------------------------
// k_S: MFMA bf16 GEMM  S[i][j] = Cb16[i][:].Qw3[j][:] + sc[i] + sq[j] (K=512).
// BK=128. Epilogue: row softmax -> P1 (LDS-staged, coalesced int4 stores);
// column partials -> colm/cols; E bf16 [b][j][i] (LDS-transposed).
__global__ __launch_bounds__(256) void k_S(const unsigned short* __restrict__ Cb16,
                                           const unsigned short* __restrict__ Qw3,
                                           const float* __restrict__ scp,
                                           const float* __restrict__ sqp,
                                           const int* __restrict__ Qmask,
                                           const int* __restrict__ Cmask,
                                           unsigned short* __restrict__ P1,
                                           unsigned short* __restrict__ Eb,
                                           float* __restrict__ colm,
                                           float* __restrict__ cols) {
    __shared__ __align__(16) char lds[49152];  // A [64][256B] @0, B [128][256B] @16384
    int lg = xcd_swz(blockIdx.x, 256);
    int b = lg >> 4, it = lg & 15, i0 = it * 64;
    int t = threadIdx.x, lane = t & 63, wv = t >> 6;
    int g = lane >> 4, r16 = lane & 15;
    const unsigned short* Asrc = Cb16 + ((size_t)b * NLC + i0) * ND;
    const unsigned short* Bsrc = Qw3 + (size_t)b * NLQ * ND;
    f32x4a zero = {0.f, 0.f, 0.f, 0.f};
    f32x4a acc[8];
#pragma unroll
    for (int nf = 0; nf < 8; ++nf) acc[nf] = zero;

    for (int kk = 0; kk < 4; ++kk) {   // K-step = 128
#pragma unroll
        for (int p = 0; p < 4; ++p) {  // A: 64 rows x 128 d = 1024 int4
            int u = t + p * 256;
            int i = u >> 4, db = u & 15;
            int4 v = *(const int4*)(Asrc + (size_t)i * ND + kk * 128 + db * 8);
            *(int4*)(lds + i * 256 + ((db * 16) ^ ((i & 7) << 4))) = v;
        }
#pragma unroll
        for (int p = 0; p < 8; ++p) {  // B: 128 rows x 128 d = 2048 int4
            int u = t + p * 256;
            int j = u >> 4, db = u & 15;
            int4 v = *(const int4*)(Bsrc + (size_t)j * ND + kk * 128 + db * 8);
            *(int4*)(lds + 16384 + j * 256 + ((db * 16) ^ ((j & 7) << 4))) = v;
        }
        __syncthreads();
#pragma unroll
        for (int ks = 0; ks < 4; ++ks) {
            int inner = ks * 64 + g * 16;
            bf16x8f a = *(const bf16x8f*)(lds + (16 * wv + r16) * 256 + (inner ^ ((r16 & 7) << 4)));
#pragma unroll
            for (int nf = 0; nf < 8; ++nf) {
                bf16x8f bq = *(const bf16x8f*)(lds + 16384 + (16 * nf + r16) * 256 + (inner ^ ((r16 & 7) << 4)));
                acc[nf] = __builtin_amdgcn_mfma_f32_16x16x32_bf16(a, bq, acc[nf], 0, 0, 0);
            }
        }
        __syncthreads();
    }

    // sv[nf][reg]: i = i0 + 16wv + 4g + reg ; j = 16nf + r16
    const float* scp0 = scp + b * NLC + i0;
    const float* scp1 = scp + NB * NLC + b * NLC + i0;
    const float* sqp0 = sqp + b * NLQ;
    const float* sqp1 = sqp + NB * NLQ + b * NLQ;
    const int* qm = Qmask + b * NLQ;
    const int* cmb = Cmask + b * NLC;
    float sv[8][4];
    float scr[4];
#pragma unroll
    for (int reg = 0; reg < 4; ++reg) {
        int il = 16 * wv + 4 * g + reg;
        scr[reg] = scp0[il] + scp1[il];
    }
    int qmv[8];
#pragma unroll
    for (int nf = 0; nf < 8; ++nf) {
        int jl = 16 * nf + r16;
        qmv[nf] = qm[jl];
        float sqv = sqp0[jl] + sqp1[jl];
#pragma unroll
        for (int reg = 0; reg < 4; ++reg) sv[nf][reg] = acc[nf][reg] + scr[reg] + sqv;
    }

    // ---- row softmax -> P1 (staged in LDS, coalesced stores) ----
    // Pl: [64 i][136 pitch] bf16 @ lds+0 (17,408 B; cpm/cps/mtl live at 20480+).
    unsigned short* Pl = (unsigned short*)lds;
#pragma unroll
    for (int reg = 0; reg < 4; ++reg) {
        float m = -INFINITY;
#pragma unroll
        for (int nf = 0; nf < 8; ++nf) m = fmaxf(m, qmv[nf] ? NEGV : sv[nf][reg]);
#pragma unroll
        for (int off = 8; off >= 1; off >>= 1) m = fmaxf(m, __shfl_xor(m, off, 64));
        float pv[8], s = 0.f;
#pragma unroll
        for (int nf = 0; nf < 8; ++nf) {
            pv[nf] = __expf((qmv[nf] ? NEGV : sv[nf][reg]) - m);
            s += pv[nf];
        }
#pragma unroll
        for (int off = 8; off >= 1; off >>= 1) s += __shfl_xor(s, off, 64);
        float rsi = 1.0f / s;
        int i = 16 * wv + 4 * g + reg;
#pragma unroll
        for (int nf = 0; nf < 8; ++nf)
            Pl[i * 136 + 16 * nf + r16] = f2bf(pv[nf] * rsi);
    }
    __syncthreads();
    {   // coalesced P1 stores: 64 rows x 16 int4 = 1024 tasks, 4/thread
        unsigned short* P1p = P1 + ((size_t)b * NLC + i0) * NLQ;
#pragma unroll
        for (int p = 0; p < 4; ++p) {
            int u = t + p * 256;
            int row = u >> 4, seg = u & 15;
            int4 v = *(const int4*)&Pl[row * 136 + seg * 8];
            *(int4*)&P1p[(size_t)row * NLQ + seg * 8] = v;
        }
    }

    // ---- column partials over this tile's 64 i's ----
    int cmv[4];
#pragma unroll
    for (int reg = 0; reg < 4; ++reg) cmv[reg] = cmb[i0 + 16 * wv + 4 * g + reg];
    float vm2[8][4];
#pragma unroll
    for (int nf = 0; nf < 8; ++nf)
#pragma unroll
        for (int reg = 0; reg < 4; ++reg) vm2[nf][reg] = cmv[reg] ? NEGV : sv[nf][reg];

    float* cpm = (float*)(lds + 20480);
    float* cps = (float*)(lds + 22528);
    float* mtl = (float*)(lds + 24576);
    float cm8[8], cs8[8];
#pragma unroll
    for (int nf = 0; nf < 8; ++nf) {
        float m = vm2[nf][0];
#pragma unroll
        for (int reg = 1; reg < 4; ++reg) m = fmaxf(m, vm2[nf][reg]);
        float s = 0.f;
#pragma unroll
        for (int reg = 0; reg < 4; ++reg) s += __expf(vm2[nf][reg] - m);
#pragma unroll
        for (int off = 16; off <= 32; off <<= 1) {
            float mo = __shfl_xor(m, off, 64);
            float so = __shfl_xor(s, off, 64);
            float mn = fmaxf(m, mo);
            s = s * __expf(m - mn) + so * __expf(mo - mn);
            m = mn;
        }
        cm8[nf] = m; cs8[nf] = s;
    }
    if (g == 0) {
#pragma unroll
        for (int nf = 0; nf < 8; ++nf) {
            cpm[(wv * 8 + nf) * 16 + r16] = cm8[nf];
            cps[(wv * 8 + nf) * 16 + r16] = cs8[nf];
        }
    }
    __syncthreads();
    if (t < 128) {
        int j = t, nf = j >> 4, rr = j & 15;
        float M = cpm[(0 * 8 + nf) * 16 + rr];
        float S = cps[(0 * 8 + nf) * 16 + rr];
#pragma unroll
        for (int w2 = 1; w2 < 4; ++w2) {
            float mo = cpm[(w2 * 8 + nf) * 16 + rr];
            float so = cps[(w2 * 8 + nf) * 16 + rr];
            float mn = fmaxf(M, mo);
            S = S * __expf(M - mn) + so * __expf(mo - mn);
            M = mn;
        }
        colm[((size_t)b * 16 + it) * NLQ + j] = M;
        cols[((size_t)b * 16 + it) * NLQ + j] = S;
        mtl[j] = M;
    }
    __syncthreads();

    // ---- E bf16 [b][j][i] via LDS transpose ----
    unsigned short* ex = (unsigned short*)lds;  // [128][80]
#pragma unroll
    for (int nf = 0; nf < 8; ++nf) {
        float mj = mtl[16 * nf + r16];
        unsigned short e4[4];
#pragma unroll
        for (int reg = 0; reg < 4; ++reg) e4[reg] = f2bf(__expf(vm2[nf][reg] - mj));
        *(uint2*)&ex[(16 * nf + r16) * 80 + 16 * wv + 4 * g] = *(uint2*)e4;
    }
    __syncthreads();
    {
        int j = t >> 1, half = t & 1;
        unsigned short* Ep = Eb + ((size_t)b * NLQ + j) * NLC + i0 + half * 32;
#pragma unroll
        for (int c = 0; c < 4; ++c)
            *(int4*)&Ep[c * 8] = *(int4*)&ex[j * 80 + half * 32 + c * 8];
    }
}

// ---------------------------------------------------------------------------
// k_s2tc (kc=1): Vt[b][d][j] = bf16( sum_it f[it][j]*(E_it^T Ct_it)[j][d] )
// Grid 128 blocks (one (b,dt) each), reg-prefetch software pipeline.
__global__ __launch_bounds__(256) void k_s2tc(const unsigned short* __restrict__ Eb,
                                              const unsigned short* __restrict__ Ct,
                                              const float* __restrict__ colm,
                                              const float* __restrict__ cols,
                                              unsigned short* __restrict__ Vt) {
    __shared__ __align__(16) char lds[23552];  // f @0 (8K), A @8192 (10240), B @18432 (5120)
    int lg = xcd_swz(blockIdx.x, 128);
    int b = lg >> 3, dt = lg & 7;
    int t = threadIdx.x, lane = t & 63, wv = t >> 6, g = lane >> 4, r16 = lane & 15;
    float* fb = (float*)lds;

    if (t < 128) {  // global col stats + per-tile scale f
        int j = t;
        const float* cmp = colm + (size_t)b * 16 * NLQ + j;
        const float* csp = cols + (size_t)b * 16 * NLQ + j;
        float M = -INFINITY;
#pragma unroll
        for (int p = 0; p < 16; ++p) M = fmaxf(M, cmp[p * NLQ]);
        float S = 0.f;
#pragma unroll
        for (int p = 0; p < 16; ++p) S += csp[p * NLQ] * __expf(cmp[p * NLQ] - M);
        float inv = 1.0f / S;
#pragma unroll
        for (int p = 0; p < 16; ++p) fb[p * NLQ + j] = __expf(cmp[p * NLQ] - M) * inv;
    }

    const unsigned short* Ebb = Eb + (size_t)b * NLQ * NLC;
    const unsigned short* Ctb = Ct + ((size_t)b * ND + dt * 64) * NLC;
    int ja0 = t >> 2, ca0 = (t & 3) * 8;
    int ja1 = (t + 256) >> 2, ca1 = ((t + 256) & 3) * 8;
    int db0 = t >> 2, cb0 = (t & 3) * 8;

    f32x4a zero = {0.f, 0.f, 0.f, 0.f};
    f32x4a acc2[2][4], V[2][4];
#pragma unroll
    for (int mf = 0; mf < 2; ++mf)
#pragma unroll
        for (int nf = 0; nf < 4; ++nf) { acc2[mf][nf] = zero; V[mf][nf] = zero; }

    int4 ra0 = *(const int4*)(Ebb + (size_t)ja0 * NLC + ca0);
    int4 ra1 = *(const int4*)(Ebb + (size_t)ja1 * NLC + ca1);
    int4 rb  = *(const int4*)(Ctb + (size_t)db0 * NLC + cb0);
    __syncthreads();  // fb ready

    for (int ib = 0; ib < NLC; ib += 32) {
        *(int4*)(lds + 8192 + (ja0 * 40 + ca0) * 2) = ra0;
        *(int4*)(lds + 8192 + (ja1 * 40 + ca1) * 2) = ra1;
        *(int4*)(lds + 18432 + (db0 * 40 + cb0) * 2) = rb;
        __syncthreads();
        if (ib + 32 < NLC) {
            ra0 = *(const int4*)(Ebb + (size_t)ja0 * NLC + ib + 32 + ca0);
            ra1 = *(const int4*)(Ebb + (size_t)ja1 * NLC + ib + 32 + ca1);
            rb  = *(const int4*)(Ctb + (size_t)db0 * NLC + ib + 32 + cb0);
        }
#pragma unroll
        for (int mf = 0; mf < 2; ++mf) {
            bf16x8f a = *(const bf16x8f*)(lds + 8192 + ((32 * wv + 16 * mf + r16) * 40 + g * 8) * 2);
#pragma unroll
            for (int nf = 0; nf < 4; ++nf) {
                bf16x8f bb = *(const bf16x8f*)(lds + 18432 + ((16 * nf + r16) * 40 + g * 8) * 2);
                acc2[mf][nf] = __builtin_amdgcn_mfma_f32_16x16x32_bf16(a, bb, acc2[mf][nf], 0, 0, 0);
            }
        }
        __syncthreads();
        if (ib & 32) {
            int itg = ib >> 6;
#pragma unroll
            for (int mf = 0; mf < 2; ++mf) {
                f32x4a f4 = *(const f32x4a*)(lds + (itg * NLQ + 32 * wv + 16 * mf + 4 * g) * 4);
#pragma unroll
                for (int nf = 0; nf < 4; ++nf) {
#pragma unroll
                    for (int reg = 0; reg < 4; ++reg)
                        V[mf][nf][reg] += f4[reg] * acc2[mf][nf][reg];
                    acc2[mf][nf] = zero;
                }
            }
        }
    }
    unsigned short* vb = Vt + ((size_t)b * ND + dt * 64) * NLQ;
#pragma unroll
    for (int mf = 0; mf < 2; ++mf)
#pragma unroll
        for (int nf = 0; nf < 4; ++nf) {
            unsigned short o[4];
#pragma unroll
            for (int reg = 0; reg < 4; ++reg) o[reg] = f2bf(V[mf][nf][reg]);
            *(uint2*)&vb[(size_t)(16 * nf + r16) * NLQ + 32 * wv + 16 * mf + 4 * g] = *(uint2*)o;
        }
}

// ---------------------------------------------------------------------------
// k_out: A = P1@Qt^T, Bv = P1@Vt^T (K=128, MFMA); out = [C, A, C*A, C*Bv].
// C read as bf16 (Cb16); loads issued at kernel entry. Grid 2048, swizzled.
__global__ __launch_bounds__(256) void k_out(const unsigned short* __restrict__ P1,
                                             const unsigned short* __restrict__ Qt,
                                             const unsigned short* __restrict__ Vt,
                                             const unsigned short* __restrict__ Cb16,
                                             float* __restrict__ Out) {
    __shared__ __align__(16) char lds[49152];
    int lg = xcd_swz(blockIdx.x, 2048);
    int b = lg >> 7, rem = lg & 127, it = rem >> 3, dt = rem & 7;
    int i0 = it * 64, d0 = dt * 64;
    int t = threadIdx.x, lane = t & 63, wv = t >> 6, g = lane >> 4, r16 = lane & 15;

    // Issue C (bf16) loads first — consumed only in the epilogue.
    const unsigned short* Cb = Cb16 + ((size_t)b * NLC + i0) * ND + d0;
    uint2 cpre[4];
#pragma unroll
    for (int p = 0; p < 4; ++p) {
        int u = t + p * 256;
        cpre[p] = *(const uint2*)&Cb[(size_t)(u >> 4) * ND + (u & 15) * 4];
    }

    const unsigned short* P1b = P1 + ((size_t)b * NLC + i0) * NLQ;
    const unsigned short* Qtb = Qt + ((size_t)b * ND + d0) * NLQ;
    const unsigned short* Vtb = Vt + ((size_t)b * ND + d0) * NLQ;
#pragma unroll
    for (int p = 0; p < 4; ++p) {
        int u = t + p * 256;
        int r = u >> 4, c = u & 15;
        int swz = (c * 16) ^ ((r & 7) << 4);
        *(int4*)(lds + r * 256 + swz) = *(const int4*)(P1b + (size_t)r * NLQ + c * 8);
        *(int4*)(lds + 16384 + r * 256 + swz) = *(const int4*)(Qtb + (size_t)r * NLQ + c * 8);
        *(int4*)(lds + 32768 + r * 256 + swz) = *(const int4*)(Vtb + (size_t)r * NLQ + c * 8);
    }
    __syncthreads();
    f32x4a zero = {0.f, 0.f, 0.f, 0.f};
    f32x4a accA[4], accB[4];
#pragma unroll
    for (int nf = 0; nf < 4; ++nf) { accA[nf] = zero; accB[nf] = zero; }
#pragma unroll
    for (int ks = 0; ks < 4; ++ks) {
        int inner = ks * 64 + g * 16;
        bf16x8f a = *(const bf16x8f*)(lds + (16 * wv + r16) * 256 + (inner ^ ((r16 & 7) << 4)));
#pragma unroll
        for (int nf = 0; nf < 4; ++nf) {
            int ro = (16 * nf + r16) * 256 + (inner ^ ((r16 & 7) << 4));
            bf16x8f q = *(const bf16x8f*)(lds + 16384 + ro);
            accA[nf] = __builtin_amdgcn_mfma_f32_16x16x32_bf16(a, q, accA[nf], 0, 0, 0);
            bf16x8f vv = *(const bf16x8f*)(lds + 32768 + ro);
            accB[nf] = __builtin_amdgcn_mfma_f32_16x16x32_bf16(a, vv, accB[nf], 0, 0, 0);
        }
    }
    __syncthreads();  // LDS staging done; reuse for accumulator transpose

    // Scatter fragments to LDS: At/Bt [64 i][68 pitch] f32.
    float* At = (float*)lds;               // 17,408 B
    float* Bt = (float*)(lds + 17408);     // 17,408 B
#pragma unroll
    for (int nf = 0; nf < 4; ++nf) {
        int dloc = 16 * nf + r16;
#pragma unroll
        for (int reg = 0; reg < 4; ++reg) {
            int iloc = 16 * wv + 4 * g + reg;
            At[iloc * 68 + dloc] = accA[nf][reg];
            Bt[iloc * 68 + dloc] = accB[nf][reg];
        }
    }
    __syncthreads();

    // Coalesced epilogue: 64 rows x 16 float4-cols = 1024 tasks, 4/thread.
    float* Ob = Out + ((size_t)b * NLC + i0) * (4 * ND);
#pragma unroll
    for (int p = 0; p < 4; ++p) {
        int u = t + p * 256;
        int row = u >> 4, c4 = (u & 15) * 4;
        uint2 cu = cpre[p];
        f32x4a cv;
        cv[0] = __uint_as_float((cu.x & 0xffffu) << 16);
        cv[1] = __uint_as_float(cu.x & 0xffff0000u);
        cv[2] = __uint_as_float((cu.y & 0xffffu) << 16);
        cv[3] = __uint_as_float(cu.y & 0xffff0000u);
        f32x4a av = *(const f32x4a*)&At[row * 68 + c4];
        f32x4a bv = *(const f32x4a*)&Bt[row * 68 + c4];
        f32x4a ca = cv * av;
        f32x4a cb = cv * bv;
        float* orow = Ob + (size_t)row * (4 * ND);
        *(f32x4a*)&orow[d0 + c4] = cv;
        *(f32x4a*)&orow[ND + d0 + c4] = av;
        *(f32x4a*)&orow[2 * ND + d0 + c4] = ca;
        *(f32x4a*)&orow[3 * ND + d0 + c4] = cb;
    }
}

// ---------------------------------------------------------------------------
extern "C" void kernel_launch(void* const* d_in, const int* in_sizes, int n_in,
                              void* d_out, int out_size, void* d_ws, size_t ws_size,
                              hipStream_t stream) {
    const float* C = (const float*)d_in[0];
    const float* Q = (const float*)d_in[1];
    const int* Cmask = (const int*)d_in[2];
    const int* Qmask = (const int*)d_in[3];
    const float* w = (const float*)d_in[4];
    float* out = (float*)d_out;

    // Early-stage scratch in d_out (all consumed before k_out overwrites it).
    char* ob = (char*)d_out;
    unsigned short* Ct  = (unsigned short*)(ob + 0);          // 16,777,216
    unsigned short* Eb  = (unsigned short*)(ob + 16777216);   //  4,194,304
    unsigned short* Qw3 = (unsigned short*)(ob + 20971520);   //  2,097,152
    float*          colm = (float*)(ob + 23068672);           //    131,072
    float*          colsv = (float*)(ob + 23199744);          //    131,072
    float*          scp  = (float*)(ob + 23330816);           //    131,072 (2 x 64K)
    float*          sqp  = (float*)(ob + 23461888);           //     16,384 (2 x 8K)

    // Final-stage scratch in ws (live while k_out writes d_out): ~25 MB.
    char* wb = (char*)d_ws;
    unsigned short* P1 = (unsigned short*)(wb + 73728);    //  4,194,304
    unsigned short* Qt = (unsigned short*)(wb + 4268032);  //  2,097,152
    unsigned short* Vt = (unsigned short*)(wb + 6365184);  //  2,097,152
    unsigned short* Cb16 = (unsigned short*)(wb + 8462336); // 16,777,216

    k_prep2<<<dim3(576), dim3(512), 0, stream>>>(C, Q, w, Cb16, Ct, Qw3, Qt, scp, sqp);
    k_S<<<dim3(256), dim3(256), 0, stream>>>(Cb16, Qw3, scp, sqp, Qmask, Cmask, P1, Eb, colm, colsv);
    k_s2tc<<<dim3(128), dim3(256), 0, stream>>>(Eb, Ct, colm, colsv, Vt);
    k_out<<<dim3(2048), dim3(256), 0, stream>>>(P1, Qt, Vt, Cb16, out);
}

// Round 17
// 75.675 us; speedup vs baseline: 1.0117x; 1.0117x over previous
//
#include <hip/hip_runtime.h>
#include <hip/hip_bf16.h>
#include <math.h>

#define NB 16
#define NLC 1024
#define NLQ 128
#define ND 512
#define NEGV (-1.0e10f)

typedef __attribute__((ext_vector_type(8))) short bf16x8f;
typedef __attribute__((ext_vector_type(4))) float f32x4a;

__device__ inline unsigned short f2bf(float f) {
    unsigned u = __float_as_uint(f);
    unsigned r = (u + 0x7fffu + ((u >> 16) & 1u)) >> 16;
    return (unsigned short)r;
}

// XCD-locality swizzle (m157 bijective form, nwg % 8 == 0).
__device__ inline int xcd_swz(int bid, int nwg) {
    int chunk = nwg >> 3;
    return (bid & 7) * chunk + (bid >> 3);
}

// ---------------------------------------------------------------------------
// k_prep2 (512 thr, 64-row x 256-d tiles, 576 blocks): single pass:
//   Cb16 bf16 [b][i][d] = C ; Ct bf16 [b][d][i] = C^T ; scp = partial C@w1
//   Qw3  bf16 [b][j][d] = Q*w3 ; Qt bf16 [b][d][j] = Q^T ; sqp = partial Q@w2
// (w3 folded into the Q side: (C*w3)@Q^T == C@(Q*w3)^T, so the row-major C
// copy is PLAIN bf16 — reused by k_out's epilogue at half the f32 bytes.)
__global__ __launch_bounds__(512) void k_prep2(const float* __restrict__ C,
                                               const float* __restrict__ Q,
                                               const float* __restrict__ w,
                                               unsigned short* __restrict__ Cb16,
                                               unsigned short* __restrict__ Ct,
                                               unsigned short* __restrict__ Qw3,
                                               unsigned short* __restrict__ Qt,
                                               float* __restrict__ scp,
                                               float* __restrict__ sqp) {
    __shared__ float T[64][65];
    int x = blockIdx.x, t = threadIdx.x;
    const float* src; const float* wdot; const float* wmul;
    unsigned short* rout; unsigned short* tout; float* sdst;
    int rows;
    if (x < 512) {
        int b = x >> 5, rt = (x >> 1) & 15, dh = x & 1;
        src = C + ((size_t)b * NLC + rt * 64) * ND + dh * 256;
        wdot = w + dh * 256;
        wmul = nullptr;                     // plain bf16(C)
        rout = Cb16 + ((size_t)b * NLC + rt * 64) * ND + dh * 256;
        tout = Ct + ((size_t)b * ND + dh * 256) * NLC + rt * 64;
        sdst = scp + dh * (NB * NLC) + b * NLC + rt * 64;
        rows = NLC;
    } else {
        int xq = x - 512;
        int b = xq >> 2, rt = (xq >> 1) & 1, dh = xq & 1;
        src = Q + ((size_t)b * NLQ + rt * 64) * ND + dh * 256;
        wdot = w + ND + dh * 256;
        wmul = w + 2 * ND + dh * 256;       // bf16(Q*w3)
        rout = Qw3 + ((size_t)b * NLQ + rt * 64) * ND + dh * 256;
        tout = Qt + ((size_t)b * ND + dh * 256) * NLQ + rt * 64;
        sdst = sqp + dh * (NB * NLQ) + b * NLQ + rt * 64;
        rows = NLQ;
    }
    int r = t >> 3;          // 0..63 row in tile
    int s8 = (t & 7) * 8;    // col offset within 64-d chunk
    float dacc = 0.f;
    for (int c = 0; c < 4; ++c) {   // 4 x 64-d chunks = 256 d
        int dbase = c * 64 + s8;
        float4 v0 = *(const float4*)&src[(size_t)r * ND + dbase];
        float4 v1 = *(const float4*)&src[(size_t)r * ND + dbase + 4];
        float4 wd0 = *(const float4*)&wdot[dbase];
        float4 wd1 = *(const float4*)&wdot[dbase + 4];
        dacc += v0.x * wd0.x + v0.y * wd0.y + v0.z * wd0.z + v0.w * wd0.w;
        dacc += v1.x * wd1.x + v1.y * wd1.y + v1.z * wd1.z + v1.w * wd1.w;
        float f8[8] = {v0.x, v0.y, v0.z, v0.w, v1.x, v1.y, v1.z, v1.w};
        unsigned short o[8];
        if (wmul) {
            float4 w30 = *(const float4*)&wmul[dbase];
            float4 w31 = *(const float4*)&wmul[dbase + 4];
            float m8[8] = {w30.x, w30.y, w30.z, w30.w, w31.x, w31.y, w31.z, w31.w};
#pragma unroll
            for (int e = 0; e < 8; ++e) o[e] = f2bf(f8[e] * m8[e]);
        } else {
#pragma unroll
            for (int e = 0; e < 8; ++e) o[e] = f2bf(f8[e]);
        }
        *(int4*)&rout[(size_t)r * ND + dbase] = *(int4*)o;
#pragma unroll
        for (int e = 0; e < 8; ++e) T[r][s8 + e] = f8[e];
        __syncthreads();
        {   // transposed bf16 out: d-row = c*64+dd, full 128B line per row
            int dd = t >> 3, seg = (t & 7) * 8;
            unsigned short o16[8];
#pragma unroll
            for (int e = 0; e < 8; ++e) o16[e] = f2bf(T[seg + e][dd]);
            *(int4*)&tout[(size_t)(c * 64 + dd) * rows + seg] = *(int4*)o16;
        }
        __syncthreads();
    }
    dacc += __shfl_xor(dacc, 1, 64);
    dacc += __shfl_xor(dacc, 2, 64);
    dacc += __shfl_xor(dacc, 4, 64);
    if ((t & 7) == 0) sdst[r] = dacc;
}

// ---------------------------------------------------------------------------
// k_S: MFMA bf16 GEMM  S[i][j] = Cb16[i][:].Qw3[j][:] + sc[i] + sq[j] (K=512).
// BK=128. Epilogue: row softmax -> P1; column partials -> colm/cols;
// E bf16 [b][j][i] (LDS-transposed). Grid 256, XCD-swizzled b-major.
__global__ __launch_bounds__(256) void k_S(const unsigned short* __restrict__ Cb16,
                                           const unsigned short* __restrict__ Qw3,
                                           const float* __restrict__ scp,
                                           const float* __restrict__ sqp,
                                           const int* __restrict__ Qmask,
                                           const int* __restrict__ Cmask,
                                           unsigned short* __restrict__ P1,
                                           unsigned short* __restrict__ Eb,
                                           float* __restrict__ colm,
                                           float* __restrict__ cols) {
    __shared__ __align__(16) char lds[49152];  // A [64][256B] @0, B [128][256B] @16384
    int lg = xcd_swz(blockIdx.x, 256);
    int b = lg >> 4, it = lg & 15, i0 = it * 64;
    int t = threadIdx.x, lane = t & 63, wv = t >> 6;
    int g = lane >> 4, r16 = lane & 15;
    const unsigned short* Asrc = Cb16 + ((size_t)b * NLC + i0) * ND;
    const unsigned short* Bsrc = Qw3 + (size_t)b * NLQ * ND;
    f32x4a zero = {0.f, 0.f, 0.f, 0.f};
    f32x4a acc[8];
#pragma unroll
    for (int nf = 0; nf < 8; ++nf) acc[nf] = zero;

    for (int kk = 0; kk < 4; ++kk) {   // K-step = 128
#pragma unroll
        for (int p = 0; p < 4; ++p) {  // A: 64 rows x 128 d = 1024 int4
            int u = t + p * 256;
            int i = u >> 4, db = u & 15;
            int4 v = *(const int4*)(Asrc + (size_t)i * ND + kk * 128 + db * 8);
            *(int4*)(lds + i * 256 + ((db * 16) ^ ((i & 7) << 4))) = v;
        }
#pragma unroll
        for (int p = 0; p < 8; ++p) {  // B: 128 rows x 128 d = 2048 int4
            int u = t + p * 256;
            int j = u >> 4, db = u & 15;
            int4 v = *(const int4*)(Bsrc + (size_t)j * ND + kk * 128 + db * 8);
            *(int4*)(lds + 16384 + j * 256 + ((db * 16) ^ ((j & 7) << 4))) = v;
        }
        __syncthreads();
#pragma unroll
        for (int ks = 0; ks < 4; ++ks) {
            int inner = ks * 64 + g * 16;
            bf16x8f a = *(const bf16x8f*)(lds + (16 * wv + r16) * 256 + (inner ^ ((r16 & 7) << 4)));
#pragma unroll
            for (int nf = 0; nf < 8; ++nf) {
                bf16x8f bq = *(const bf16x8f*)(lds + 16384 + (16 * nf + r16) * 256 + (inner ^ ((r16 & 7) << 4)));
                acc[nf] = __builtin_amdgcn_mfma_f32_16x16x32_bf16(a, bq, acc[nf], 0, 0, 0);
            }
        }
        __syncthreads();
    }

    // sv[nf][reg]: i = i0 + 16wv + 4g + reg ; j = 16nf + r16
    const float* scp0 = scp + b * NLC + i0;
    const float* scp1 = scp + NB * NLC + b * NLC + i0;
    const float* sqp0 = sqp + b * NLQ;
    const float* sqp1 = sqp + NB * NLQ + b * NLQ;
    const int* qm = Qmask + b * NLQ;
    const int* cmb = Cmask + b * NLC;
    float sv[8][4];
    float scr[4];
#pragma unroll
    for (int reg = 0; reg < 4; ++reg) {
        int il = 16 * wv + 4 * g + reg;
        scr[reg] = scp0[il] + scp1[il];
    }
    int qmv[8];
#pragma unroll
    for (int nf = 0; nf < 8; ++nf) {
        int jl = 16 * nf + r16;
        qmv[nf] = qm[jl];
        float sqv = sqp0[jl] + sqp1[jl];
#pragma unroll
        for (int reg = 0; reg < 4; ++reg) sv[nf][reg] = acc[nf][reg] + scr[reg] + sqv;
    }

    // ---- row softmax -> P1 ----
    unsigned short* P1p = P1 + ((size_t)b * NLC + i0) * NLQ;
#pragma unroll
    for (int reg = 0; reg < 4; ++reg) {
        float m = -INFINITY;
#pragma unroll
        for (int nf = 0; nf < 8; ++nf) m = fmaxf(m, qmv[nf] ? NEGV : sv[nf][reg]);
#pragma unroll
        for (int off = 8; off >= 1; off >>= 1) m = fmaxf(m, __shfl_xor(m, off, 64));
        float pv[8], s = 0.f;
#pragma unroll
        for (int nf = 0; nf < 8; ++nf) {
            pv[nf] = __expf((qmv[nf] ? NEGV : sv[nf][reg]) - m);
            s += pv[nf];
        }
#pragma unroll
        for (int off = 8; off >= 1; off >>= 1) s += __shfl_xor(s, off, 64);
        float rsi = 1.0f / s;
        int i = 16 * wv + 4 * g + reg;
#pragma unroll
        for (int nf = 0; nf < 8; ++nf)
            P1p[(size_t)i * NLQ + 16 * nf + r16] = f2bf(pv[nf] * rsi);
    }

    // ---- column partials over this tile's 64 i's ----
    int cmv[4];
#pragma unroll
    for (int reg = 0; reg < 4; ++reg) cmv[reg] = cmb[i0 + 16 * wv + 4 * g + reg];
    float vm2[8][4];
#pragma unroll
    for (int nf = 0; nf < 8; ++nf)
#pragma unroll
        for (int reg = 0; reg < 4; ++reg) vm2[nf][reg] = cmv[reg] ? NEGV : sv[nf][reg];

    float* cpm = (float*)(lds + 20480);
    float* cps = (float*)(lds + 22528);
    float* mtl = (float*)(lds + 24576);
    float cm8[8], cs8[8];
#pragma unroll
    for (int nf = 0; nf < 8; ++nf) {
        float m = vm2[nf][0];
#pragma unroll
        for (int reg = 1; reg < 4; ++reg) m = fmaxf(m, vm2[nf][reg]);
        float s = 0.f;
#pragma unroll
        for (int reg = 0; reg < 4; ++reg) s += __expf(vm2[nf][reg] - m);
#pragma unroll
        for (int off = 16; off <= 32; off <<= 1) {
            float mo = __shfl_xor(m, off, 64);
            float so = __shfl_xor(s, off, 64);
            float mn = fmaxf(m, mo);
            s = s * __expf(m - mn) + so * __expf(mo - mn);
            m = mn;
        }
        cm8[nf] = m; cs8[nf] = s;
    }
    if (g == 0) {
#pragma unroll
        for (int nf = 0; nf < 8; ++nf) {
            cpm[(wv * 8 + nf) * 16 + r16] = cm8[nf];
            cps[(wv * 8 + nf) * 16 + r16] = cs8[nf];
        }
    }
    __syncthreads();
    if (t < 128) {
        int j = t, nf = j >> 4, rr = j & 15;
        float M = cpm[(0 * 8 + nf) * 16 + rr];
        float S = cps[(0 * 8 + nf) * 16 + rr];
#pragma unroll
        for (int w2 = 1; w2 < 4; ++w2) {
            float mo = cpm[(w2 * 8 + nf) * 16 + rr];
            float so = cps[(w2 * 8 + nf) * 16 + rr];
            float mn = fmaxf(M, mo);
            S = S * __expf(M - mn) + so * __expf(mo - mn);
            M = mn;
        }
        colm[((size_t)b * 16 + it) * NLQ + j] = M;
        cols[((size_t)b * 16 + it) * NLQ + j] = S;
        mtl[j] = M;
    }
    __syncthreads();

    // ---- E bf16 [b][j][i] via LDS transpose ----
    unsigned short* ex = (unsigned short*)lds;  // [128][80]
#pragma unroll
    for (int nf = 0; nf < 8; ++nf) {
        float mj = mtl[16 * nf + r16];
        unsigned short e4[4];
#pragma unroll
        for (int reg = 0; reg < 4; ++reg) e4[reg] = f2bf(__expf(vm2[nf][reg] - mj));
        *(uint2*)&ex[(16 * nf + r16) * 80 + 16 * wv + 4 * g] = *(uint2*)e4;
    }
    __syncthreads();
    {
        int j = t >> 1, half = t & 1;
        unsigned short* Ep = Eb + ((size_t)b * NLQ + j) * NLC + i0 + half * 32;
#pragma unroll
        for (int c = 0; c < 4; ++c)
            *(int4*)&Ep[c * 8] = *(int4*)&ex[j * 80 + half * 32 + c * 8];
    }
}

// ---------------------------------------------------------------------------
// k_s2tc (kc=1): Vt[b][d][j] = bf16( sum_it f[it][j]*(E_it^T Ct_it)[j][d] )
// Grid 128 blocks (one (b,dt) each), reg-prefetch software pipeline.
__global__ __launch_bounds__(256) void k_s2tc(const unsigned short* __restrict__ Eb,
                                              const unsigned short* __restrict__ Ct,
                                              const float* __restrict__ colm,
                                              const float* __restrict__ cols,
                                              unsigned short* __restrict__ Vt) {
    __shared__ __align__(16) char lds[23552];  // f @0 (8K), A @8192 (10240), B @18432 (5120)
    int lg = xcd_swz(blockIdx.x, 128);
    int b = lg >> 3, dt = lg & 7;
    int t = threadIdx.x, lane = t & 63, wv = t >> 6, g = lane >> 4, r16 = lane & 15;
    float* fb = (float*)lds;

    if (t < 128) {  // global col stats + per-tile scale f
        int j = t;
        const float* cmp = colm + (size_t)b * 16 * NLQ + j;
        const float* csp = cols + (size_t)b * 16 * NLQ + j;
        float M = -INFINITY;
#pragma unroll
        for (int p = 0; p < 16; ++p) M = fmaxf(M, cmp[p * NLQ]);
        float S = 0.f;
#pragma unroll
        for (int p = 0; p < 16; ++p) S += csp[p * NLQ] * __expf(cmp[p * NLQ] - M);
        float inv = 1.0f / S;
#pragma unroll
        for (int p = 0; p < 16; ++p) fb[p * NLQ + j] = __expf(cmp[p * NLQ] - M) * inv;
    }

    const unsigned short* Ebb = Eb + (size_t)b * NLQ * NLC;
    const unsigned short* Ctb = Ct + ((size_t)b * ND + dt * 64) * NLC;
    int ja0 = t >> 2, ca0 = (t & 3) * 8;
    int ja1 = (t + 256) >> 2, ca1 = ((t + 256) & 3) * 8;
    int db0 = t >> 2, cb0 = (t & 3) * 8;

    f32x4a zero = {0.f, 0.f, 0.f, 0.f};
    f32x4a acc2[2][4], V[2][4];
#pragma unroll
    for (int mf = 0; mf < 2; ++mf)
#pragma unroll
        for (int nf = 0; nf < 4; ++nf) { acc2[mf][nf] = zero; V[mf][nf] = zero; }

    int4 ra0 = *(const int4*)(Ebb + (size_t)ja0 * NLC + ca0);
    int4 ra1 = *(const int4*)(Ebb + (size_t)ja1 * NLC + ca1);
    int4 rb  = *(const int4*)(Ctb + (size_t)db0 * NLC + cb0);
    __syncthreads();  // fb ready

    for (int ib = 0; ib < NLC; ib += 32) {
        *(int4*)(lds + 8192 + (ja0 * 40 + ca0) * 2) = ra0;
        *(int4*)(lds + 8192 + (ja1 * 40 + ca1) * 2) = ra1;
        *(int4*)(lds + 18432 + (db0 * 40 + cb0) * 2) = rb;
        __syncthreads();
        if (ib + 32 < NLC) {
            ra0 = *(const int4*)(Ebb + (size_t)ja0 * NLC + ib + 32 + ca0);
            ra1 = *(const int4*)(Ebb + (size_t)ja1 * NLC + ib + 32 + ca1);
            rb  = *(const int4*)(Ctb + (size_t)db0 * NLC + ib + 32 + cb0);
        }
#pragma unroll
        for (int mf = 0; mf < 2; ++mf) {
            bf16x8f a = *(const bf16x8f*)(lds + 8192 + ((32 * wv + 16 * mf + r16) * 40 + g * 8) * 2);
#pragma unroll
            for (int nf = 0; nf < 4; ++nf) {
                bf16x8f bb = *(const bf16x8f*)(lds + 18432 + ((16 * nf + r16) * 40 + g * 8) * 2);
                acc2[mf][nf] = __builtin_amdgcn_mfma_f32_16x16x32_bf16(a, bb, acc2[mf][nf], 0, 0, 0);
            }
        }
        __syncthreads();
        if (ib & 32) {
            int itg = ib >> 6;
#pragma unroll
            for (int mf = 0; mf < 2; ++mf) {
                f32x4a f4 = *(const f32x4a*)(lds + (itg * NLQ + 32 * wv + 16 * mf + 4 * g) * 4);
#pragma unroll
                for (int nf = 0; nf < 4; ++nf) {
#pragma unroll
                    for (int reg = 0; reg < 4; ++reg)
                        V[mf][nf][reg] += f4[reg] * acc2[mf][nf][reg];
                    acc2[mf][nf] = zero;
                }
            }
        }
    }
    unsigned short* vb = Vt + ((size_t)b * ND + dt * 64) * NLQ;
#pragma unroll
    for (int mf = 0; mf < 2; ++mf)
#pragma unroll
        for (int nf = 0; nf < 4; ++nf) {
            unsigned short o[4];
#pragma unroll
            for (int reg = 0; reg < 4; ++reg) o[reg] = f2bf(V[mf][nf][reg]);
            *(uint2*)&vb[(size_t)(16 * nf + r16) * NLQ + 32 * wv + 16 * mf + 4 * g] = *(uint2*)o;
        }
}

// ---------------------------------------------------------------------------
// k_out: A = P1@Qt^T, Bv = P1@Vt^T (K=128, MFMA); out = [C, A, C*A, C*Bv].
// C read as bf16 (Cb16, half the bytes); loads issued at kernel entry.
// Grid: 2048, XCD-swizzled.
__global__ __launch_bounds__(256) void k_out(const unsigned short* __restrict__ P1,
                                             const unsigned short* __restrict__ Qt,
                                             const unsigned short* __restrict__ Vt,
                                             const unsigned short* __restrict__ Cb16,
                                             float* __restrict__ Out) {
    __shared__ __align__(16) char lds[49152];
    int lg = xcd_swz(blockIdx.x, 2048);
    int b = lg >> 7, rem = lg & 127, it = rem >> 3, dt = rem & 7;
    int i0 = it * 64, d0 = dt * 64;
    int t = threadIdx.x, lane = t & 63, wv = t >> 6, g = lane >> 4, r16 = lane & 15;

    // Issue C (bf16) loads first — consumed only in the epilogue.
    const unsigned short* Cb = Cb16 + ((size_t)b * NLC + i0) * ND + d0;
    uint2 cpre[4];
#pragma unroll
    for (int p = 0; p < 4; ++p) {
        int u = t + p * 256;
        cpre[p] = *(const uint2*)&Cb[(size_t)(u >> 4) * ND + (u & 15) * 4];
    }

    const unsigned short* P1b = P1 + ((size_t)b * NLC + i0) * NLQ;
    const unsigned short* Qtb = Qt + ((size_t)b * ND + d0) * NLQ;
    const unsigned short* Vtb = Vt + ((size_t)b * ND + d0) * NLQ;
#pragma unroll
    for (int p = 0; p < 4; ++p) {
        int u = t + p * 256;
        int r = u >> 4, c = u & 15;
        int swz = (c * 16) ^ ((r & 7) << 4);
        *(int4*)(lds + r * 256 + swz) = *(const int4*)(P1b + (size_t)r * NLQ + c * 8);
        *(int4*)(lds + 16384 + r * 256 + swz) = *(const int4*)(Qtb + (size_t)r * NLQ + c * 8);
        *(int4*)(lds + 32768 + r * 256 + swz) = *(const int4*)(Vtb + (size_t)r * NLQ + c * 8);
    }
    __syncthreads();
    f32x4a zero = {0.f, 0.f, 0.f, 0.f};
    f32x4a accA[4], accB[4];
#pragma unroll
    for (int nf = 0; nf < 4; ++nf) { accA[nf] = zero; accB[nf] = zero; }
#pragma unroll
    for (int ks = 0; ks < 4; ++ks) {
        int inner = ks * 64 + g * 16;
        bf16x8f a = *(const bf16x8f*)(lds + (16 * wv + r16) * 256 + (inner ^ ((r16 & 7) << 4)));
#pragma unroll
        for (int nf = 0; nf < 4; ++nf) {
            int ro = (16 * nf + r16) * 256 + (inner ^ ((r16 & 7) << 4));
            bf16x8f q = *(const bf16x8f*)(lds + 16384 + ro);
            accA[nf] = __builtin_amdgcn_mfma_f32_16x16x32_bf16(a, q, accA[nf], 0, 0, 0);
            bf16x8f vv = *(const bf16x8f*)(lds + 32768 + ro);
            accB[nf] = __builtin_amdgcn_mfma_f32_16x16x32_bf16(a, vv, accB[nf], 0, 0, 0);
        }
    }
    __syncthreads();  // LDS staging done; reuse for accumulator transpose

    // Scatter fragments to LDS: At/Bt [64 i][68 pitch] f32.
    float* At = (float*)lds;               // 17,408 B
    float* Bt = (float*)(lds + 17408);     // 17,408 B
#pragma unroll
    for (int nf = 0; nf < 4; ++nf) {
        int dloc = 16 * nf + r16;
#pragma unroll
        for (int reg = 0; reg < 4; ++reg) {
            int iloc = 16 * wv + 4 * g + reg;
            At[iloc * 68 + dloc] = accA[nf][reg];
            Bt[iloc * 68 + dloc] = accB[nf][reg];
        }
    }
    __syncthreads();

    // Coalesced epilogue: 64 rows x 16 float4-cols = 1024 tasks, 4/thread.
    float* Ob = Out + ((size_t)b * NLC + i0) * (4 * ND);
#pragma unroll
    for (int p = 0; p < 4; ++p) {
        int u = t + p * 256;
        int row = u >> 4, c4 = (u & 15) * 4;
        uint2 cu = cpre[p];
        f32x4a cv;
        cv[0] = __uint_as_float((cu.x & 0xffffu) << 16);
        cv[1] = __uint_as_float(cu.x & 0xffff0000u);
        cv[2] = __uint_as_float((cu.y & 0xffffu) << 16);
        cv[3] = __uint_as_float(cu.y & 0xffff0000u);
        f32x4a av = *(const f32x4a*)&At[row * 68 + c4];
        f32x4a bv = *(const f32x4a*)&Bt[row * 68 + c4];
        f32x4a ca = cv * av;
        f32x4a cb = cv * bv;
        float* orow = Ob + (size_t)row * (4 * ND);
        *(f32x4a*)&orow[d0 + c4] = cv;
        *(f32x4a*)&orow[ND + d0 + c4] = av;
        *(f32x4a*)&orow[2 * ND + d0 + c4] = ca;
        *(f32x4a*)&orow[3 * ND + d0 + c4] = cb;
    }
}

// ---------------------------------------------------------------------------
extern "C" void kernel_launch(void* const* d_in, const int* in_sizes, int n_in,
                              void* d_out, int out_size, void* d_ws, size_t ws_size,
                              hipStream_t stream) {
    const float* C = (const float*)d_in[0];
    const float* Q = (const float*)d_in[1];
    const int* Cmask = (const int*)d_in[2];
    const int* Qmask = (const int*)d_in[3];
    const float* w = (const float*)d_in[4];
    float* out = (float*)d_out;

    // Early-stage scratch in d_out (all consumed before k_out overwrites it).
    char* ob = (char*)d_out;
    unsigned short* Ct  = (unsigned short*)(ob + 0);          // 16,777,216
    unsigned short* Eb  = (unsigned short*)(ob + 16777216);   //  4,194,304
    unsigned short* Qw3 = (unsigned short*)(ob + 20971520);   //  2,097,152
    float*          colm = (float*)(ob + 23068672);           //    131,072
    float*          colsv = (float*)(ob + 23199744);          //    131,072
    float*          scp  = (float*)(ob + 23330816);           //    131,072 (2 x 64K)
    float*          sqp  = (float*)(ob + 23461888);           //     16,384 (2 x 8K)

    // Final-stage scratch in ws (live while k_out writes d_out): ~25 MB.
    char* wb = (char*)d_ws;
    unsigned short* P1 = (unsigned short*)(wb + 73728);    //  4,194,304
    unsigned short* Qt = (unsigned short*)(wb + 4268032);  //  2,097,152
    unsigned short* Vt = (unsigned short*)(wb + 6365184);  //  2,097,152
    unsigned short* Cb16 = (unsigned short*)(wb + 8462336); // 16,777,216

    k_prep2<<<dim3(576), dim3(512), 0, stream>>>(C, Q, w, Cb16, Ct, Qw3, Qt, scp, sqp);
    k_S<<<dim3(256), dim3(256), 0, stream>>>(Cb16, Qw3, scp, sqp, Qmask, Cmask, P1, Eb, colm, colsv);
    k_s2tc<<<dim3(128), dim3(256), 0, stream>>>(Eb, Ct, colm, colsv, Vt);
    k_out<<<dim3(2048), dim3(256), 0, stream>>>(P1, Qt, Vt, Cb16, out);
}